// Round 9
// baseline (551.925 us; speedup 1.0000x reference)
//
#include <hip/hip_runtime.h>
#include <math.h>

#define N_PTS 65536
#define DIM   64
#define K_CL  128
#define EPSV  1e-8f
#define CAP   8192

// ---------------- ws layout (bytes) ----------------
// 0                  : fill_acc[128] float (atomics; zeroed each launch)
// 1024               : pred_x[N]     int
// 263168             : idx_x[128*CAP] int
// 263168+4194304     : idx_t[128*CAP] int
// 263168+8388608     : count_x[128] int
// +512               : count_t[128] int
// +1024              : parts[8192]  float (one slot per (cluster,feature) task)

__global__ __launch_bounds__(256) void k_zero(float* ws_f) {
  ws_f[threadIdx.x] = 0.0f;  // zeros first 1024 B: fill_acc
}

// Wave-granular K-split: block = 512 thr = 8 waves = 2 point-groups x
// 4 cluster-groups (32 clusters each). jbase is wave-uniform -> centers
// stay scalarized (s_load). Grid = 4096 waves = 4/SIMD for latency hiding.
// Pass-1 w values cached in registers across the barrier (no recompute).
__global__ __launch_bounds__(512, 4) void k_pred_fill(
    const float* __restrict__ x, const float* __restrict__ centers,
    float* __restrict__ fill_acc, int* __restrict__ pred_x)
{
  __shared__ float csq[K_CL];
  __shared__ float fill_lds[K_CL];
  __shared__ float psum[4][128];
  __shared__ float pbest[4][128];
  __shared__ int   pbj[4][128];
  __shared__ float invl[128];
  const int tid   = threadIdx.x;
  const int lane  = tid & 63;
  const int wid   = tid >> 6;        // 0..7
  const int pg    = wid & 1;         // point group
  const int jg    = wid >> 1;        // cluster group 0..3
  const int jbase = jg * 32;         // wave-uniform!
  const int pidx  = pg * 64 + lane;  // local point 0..127
  const int p     = blockIdx.x * 128 + pidx;

  if (tid < K_CL) {
    const float* cp = centers + tid * DIM;
    float s = 0.0f;
    #pragma unroll 8
    for (int d = 0; d < DIM; ++d) { float v = cp[d]; s += v * v; }
    csq[tid] = s;
    fill_lds[tid] = 0.0f;
  }

  float xr[DIM];
  const float4* xp = reinterpret_cast<const float4*>(x + (size_t)p * DIM);
  #pragma unroll
  for (int q = 0; q < DIM / 4; ++q) {
    float4 v = xp[q];
    xr[4 * q + 0] = v.x; xr[4 * q + 1] = v.y;
    xr[4 * q + 2] = v.z; xr[4 * q + 3] = v.w;
  }
  float xsq = 0.0f;
  #pragma unroll
  for (int d = 0; d < DIM; ++d) xsq += xr[d] * xr[d];
  __syncthreads();

  // ---- pass 1 over own 32 clusters: w cached in regs, partial argmin ----
  float wv[32];
  float sumw = 0.0f, best = INFINITY;
  int   bestj = jbase;
  #pragma unroll
  for (int jj = 0; jj < 32; ++jj) {
    const int j = jbase + jj;
    const float* cp = centers + j * DIM;   // uniform address -> s_load
    float d0 = 0.f, d1 = 0.f, d2a = 0.f, d3 = 0.f;
    #pragma unroll
    for (int d = 0; d < DIM; d += 4) {
      d0  += xr[d + 0] * cp[d + 0];
      d1  += xr[d + 1] * cp[d + 1];
      d2a += xr[d + 2] * cp[d + 2];
      d3  += xr[d + 3] * cp[d + 3];
    }
    float dot  = (d0 + d1) + (d2a + d3);
    float dsq  = xsq + csq[j] - 2.0f * dot;
    float dist = sqrtf(fmaxf(dsq, 0.0f));
    float ww   = 1.0f / (dist + EPSV);
    wv[jj] = ww;
    sumw += ww;
    if (dist < best) { best = dist; bestj = j; }
  }
  psum[jg][pidx]  = sumw;
  pbest[jg][pidx] = best;
  pbj[jg][pidx]   = bestj;
  __syncthreads();

  // ---- combine 4 partials per point (ascending group + strict < keeps
  // exact first-index argmin tie-break) ----
  if (tid < 128) {
    float sT = 0.0f, b = INFINITY;
    int bj = 0;
    #pragma unroll
    for (int g = 0; g < 4; ++g) {
      sT += psum[g][tid];
      float bb = pbest[g][tid];
      if (bb < b) { b = bb; bj = pbj[g][tid]; }
    }
    invl[tid] = 1.0f / sT;
    pred_x[blockIdx.x * 128 + tid] = bj;
  }
  __syncthreads();

  // ---- pass 2: normalize cached w, reduce per cluster ----
  const float invv = invl[pidx];
  #pragma unroll
  for (int jj = 0; jj < 32; ++jj) {
    float wn = wv[jj] * invv;
    wn += __shfl_down(wn, 32);
    wn += __shfl_down(wn, 16);
    wn += __shfl_down(wn, 8);
    wn += __shfl_down(wn, 4);
    wn += __shfl_down(wn, 2);
    wn += __shfl_down(wn, 1);
    if (lane == 0) atomicAdd(&fill_lds[jbase + jj], wn);
  }
  __syncthreads();
  if (tid < K_CL) atomicAdd(&fill_acc[tid], fill_lds[tid]);
}

// stable member-list build, two-phase (1 barrier instead of 128):
// wave w counts its contiguous 4096-range, prefix over waves, rescan+write.
__global__ __launch_bounds__(1024) void k_scatter(
    const int* __restrict__ pred_x, const int* __restrict__ pred_t,
    int* __restrict__ idx_x, int* __restrict__ idx_t,
    int* __restrict__ count_x, int* __restrict__ count_t)
{
  const int c    = blockIdx.x >> 1;
  const int side = blockIdx.x & 1;
  const int* __restrict__ pred = side ? pred_t : pred_x;
  int* __restrict__ out = side ? idx_t : idx_x;
  int* __restrict__ cnt = side ? count_t : count_x;

  __shared__ int wsum[16];
  const int tid = threadIdx.x, lane = tid & 63, w = tid >> 6;
  const int beg = w * 4096;

  int cw = 0;
  for (int s = 0; s < 4096; s += 64) {
    const bool m = (pred[beg + s + lane] == c);
    cw += __popcll(__ballot(m));
  }
  if (lane == 0) wsum[w] = cw;
  __syncthreads();
  int base = 0, tot = 0;
  #pragma unroll
  for (int k = 0; k < 16; ++k) { int v = wsum[k]; tot += v; if (k < w) base += v; }

  int run = base;
  for (int s = 0; s < 4096; s += 64) {
    const int i = beg + s + lane;
    const bool m = (pred[i] == c);
    unsigned long long bal = __ballot(m);
    int lp = __popcll(bal & ((1ull << lane) - 1ull));
    if (m) { int pos = run + lp; if (pos < CAP) out[c * CAP + pos] = i; }
    run += __popcll(bal);
  }
  if (tid == 0) cnt[c] = tot;
}

// ---- in-register bitonic helpers ----
__device__ __forceinline__ void ce(float& a, float& b, bool up) {
  float lo = fminf(a, b), hi = fmaxf(a, b);
  a = up ? lo : hi;
  b = up ? hi : lo;
}

__device__ __forceinline__ void merge8(float* v, bool up) {
  ce(v[0],v[4],up); ce(v[1],v[5],up); ce(v[2],v[6],up); ce(v[3],v[7],up);
  ce(v[0],v[2],up); ce(v[1],v[3],up); ce(v[4],v[6],up); ce(v[5],v[7],up);
  ce(v[0],v[1],up); ce(v[2],v[3],up); ce(v[4],v[5],up); ce(v[6],v[7],up);
}

__device__ __forceinline__ void sort8(float* v, bool up8) {
  ce(v[0],v[1],true );  ce(v[2],v[3],false); ce(v[4],v[5],true );  ce(v[6],v[7],false);
  ce(v[0],v[2],true );  ce(v[1],v[3],true );  ce(v[4],v[6],false); ce(v[5],v[7],false);
  ce(v[0],v[1],true );  ce(v[2],v[3],true );  ce(v[4],v[5],false); ce(v[6],v[7],false);
  merge8(v, up8);
}

__device__ __forceinline__ void merge16(float* v, bool up) {
  #pragma unroll
  for (int e = 0; e < 8; ++e) ce(v[e], v[e + 8], up);
  merge8(v, up);
  merge8(v + 8, up);
}

__device__ __forceinline__ void sort16(float* v, bool up16) {
  sort8(v, true);
  sort8(v + 8, false);
  merge16(v, up16);
}

// V=8: shuffle phases j=min(k/2,256)..8, then register j=4,2,1
__device__ __forceinline__ void stage_tail(float va[8], float vb[8],
                                           int ib, int k, bool up) {
  for (int j = (k >> 1) > 256 ? 256 : (k >> 1); j >= 8; j >>= 1) {
    const int  jl = j >> 3;
    const bool low = ((ib & j) == 0);
    const bool tm  = (up == low);
    #pragma unroll
    for (int e = 0; e < 8; ++e) {
      float p = __shfl_xor(va[e], jl, 64);
      va[e] = tm ? fminf(va[e], p) : fmaxf(va[e], p);
      float q = __shfl_xor(vb[e], jl, 64);
      vb[e] = tm ? fminf(vb[e], q) : fmaxf(vb[e], q);
    }
  }
  merge8(va, up);
  merge8(vb, up);
}

// V=16: shuffle phases j=min(k/2,512)..16, then register j=8..1 (merge16)
__device__ __forceinline__ void stage_tail16(float va[16], float vb[16],
                                             int ib, int k, bool up) {
  for (int j = (k >> 1) > 512 ? 512 : (k >> 1); j >= 16; j >>= 1) {
    const int  jl = j >> 4;
    const bool low = ((ib & j) == 0);
    const bool tm  = (up == low);
    #pragma unroll
    for (int e = 0; e < 16; ++e) {
      float p = __shfl_xor(va[e], jl, 64);
      va[e] = tm ? fminf(va[e], p) : fmaxf(va[e], p);
      float q = __shfl_xor(vb[e], jl, 64);
      vb[e] = tm ? fminf(vb[e], q) : fmaxf(vb[e], q);
    }
  }
  merge16(va, up);
  merge16(vb, up);
}

// Unified W1 dispatch. Blocks [0,8192): per-task role for m>1024 (adaptive
// P in {2048,4096,8192}; LDS only for j>=1024). Blocks [8192,9216): 8
// independent wave-tasks each (m<=1024; registers+shuffles, no barriers).
__global__ __launch_bounds__(512, 4) void k_w1_all(
    const float* __restrict__ x, const float* __restrict__ t,
    const int* __restrict__ idx_x, const int* __restrict__ idx_t,
    const int* __restrict__ count_x, const int* __restrict__ count_t,
    float* __restrict__ parts)
{
  __shared__ float sa[8192];   // 32 KB
  __shared__ float sb[8192];   // 32 KB
  __shared__ float red[8];
  const int tid = threadIdx.x;

  if (blockIdx.x < 8192) {
    // ---------------- per-task role (m > 1024) ----------------
    const int task = blockIdx.x;
    const int c = task >> 6, d = task & 63;
    const int m = min(min(count_x[c], CAP), min(count_t[c], CAP));
    if (m <= 1024) return;
    int P = 2048;
    while (P < m) P <<= 1;

    const int ib  = tid << 4;
    const bool active = (ib < P);
    const int gb  = c * CAP + ib;
    float va[16], vb[16];
    if (active) {
      #pragma unroll
      for (int e = 0; e < 16; ++e) {
        if (ib + e < m) {
          va[e] = x[(size_t)idx_x[gb + e] * DIM + d];
          vb[e] = t[(size_t)idx_t[gb + e] * DIM + d];
        } else { va[e] = INFINITY; vb[e] = INFINITY; }
      }
      const bool u16 = ((ib & 16) == 0);
      sort16(va, u16);
      sort16(vb, u16);
    }

    for (int k = 32; k <= P; k <<= 1) {
      const bool up = ((ib & k) == 0);
      for (int j = k >> 1; j >= 1024; j >>= 1) {
        __syncthreads();                     // WAR vs prior phase's reads
        if (active) {
          #pragma unroll
          for (int q = 0; q < 4; ++q) {
            *(float4*)&sa[ib + 4*q] = make_float4(va[4*q],va[4*q+1],va[4*q+2],va[4*q+3]);
            *(float4*)&sb[ib + 4*q] = make_float4(vb[4*q],vb[4*q+1],vb[4*q+2],vb[4*q+3]);
          }
        }
        __syncthreads();
        if (active) {
          const int pi = ib ^ j;
          const bool tm = (up == ((ib & j) == 0));
          #pragma unroll
          for (int q = 0; q < 4; ++q) {
            float4 A = *(const float4*)&sa[pi + 4*q];
            float4 B = *(const float4*)&sb[pi + 4*q];
            va[4*q+0] = tm ? fminf(va[4*q+0],A.x) : fmaxf(va[4*q+0],A.x);
            va[4*q+1] = tm ? fminf(va[4*q+1],A.y) : fmaxf(va[4*q+1],A.y);
            va[4*q+2] = tm ? fminf(va[4*q+2],A.z) : fmaxf(va[4*q+2],A.z);
            va[4*q+3] = tm ? fminf(va[4*q+3],A.w) : fmaxf(va[4*q+3],A.w);
            vb[4*q+0] = tm ? fminf(vb[4*q+0],B.x) : fmaxf(vb[4*q+0],B.x);
            vb[4*q+1] = tm ? fminf(vb[4*q+1],B.y) : fmaxf(vb[4*q+1],B.y);
            vb[4*q+2] = tm ? fminf(vb[4*q+2],B.z) : fmaxf(vb[4*q+2],B.z);
            vb[4*q+3] = tm ? fminf(vb[4*q+3],B.w) : fmaxf(vb[4*q+3],B.w);
          }
        }
      }
      if (active) stage_tail16(va, vb, ib, k, up);
    }

    float s = 0.0f;
    if (active) {
      #pragma unroll
      for (int e = 0; e < 16; ++e)
        if (ib + e < m) s += fabsf(va[e] - vb[e]);
    }
    #pragma unroll
    for (int off = 32; off > 0; off >>= 1) s += __shfl_down(s, off);
    __syncthreads();
    if ((tid & 63) == 0) red[tid >> 6] = s;
    __syncthreads();
    if (tid == 0) {
      float tot = 0.0f;
      #pragma unroll
      for (int w = 0; w < 8; ++w) tot += red[w];
      parts[task] = tot / (float)(m * DIM);
    }
  } else {
    // ---------------- wave role (m <= 1024), no barriers ----------------
    const int task = (blockIdx.x - 8192) * 8 + (tid >> 6);
    const int lane = tid & 63;
    const int c = task >> 6, d = task & 63;
    const int m = min(min(count_x[c], CAP), min(count_t[c], CAP));
    if (m > 1024) return;                    // per-task role writes this slot
    if (m == 0) { if (lane == 0) parts[task] = 0.0f; return; }

    float s = 0.0f;
    if (m <= 512) {
      int P = 8;
      while (P < m) P <<= 1;
      const int ib = lane << 3;
      const int gb = c * CAP + ib;
      float va[8], vb[8];
      #pragma unroll
      for (int e = 0; e < 8; ++e) {
        if (ib + e < m) {
          va[e] = x[(size_t)idx_x[gb + e] * DIM + d];
          vb[e] = t[(size_t)idx_t[gb + e] * DIM + d];
        } else { va[e] = INFINITY; vb[e] = INFINITY; }
      }
      const bool u8 = ((ib & 8) == 0);
      sort8(va, u8);
      sort8(vb, u8);
      for (int k = 16; k <= P; k <<= 1)
        stage_tail(va, vb, ib, k, ((ib & k) == 0));
      #pragma unroll
      for (int e = 0; e < 8; ++e)
        if (ib + e < m) s += fabsf(va[e] - vb[e]);
    } else {
      const int ib = lane << 4;              // P = 1024, all lanes active
      const int gb = c * CAP + ib;
      float va[16], vb[16];
      #pragma unroll
      for (int e = 0; e < 16; ++e) {
        if (ib + e < m) {
          va[e] = x[(size_t)idx_x[gb + e] * DIM + d];
          vb[e] = t[(size_t)idx_t[gb + e] * DIM + d];
        } else { va[e] = INFINITY; vb[e] = INFINITY; }
      }
      const bool u16 = ((ib & 16) == 0);
      sort16(va, u16);
      sort16(vb, u16);
      for (int k = 32; k <= 1024; k <<= 1)
        stage_tail16(va, vb, ib, k, ((ib & k) == 0));
      #pragma unroll
      for (int e = 0; e < 16; ++e)
        if (ib + e < m) s += fabsf(va[e] - vb[e]);
    }
    #pragma unroll
    for (int off = 32; off > 0; off >>= 1) s += __shfl_down(s, off);
    if (lane == 0) parts[task] = s / (float)(m * DIM);
  }
}

__global__ __launch_bounds__(1024) void k_final(
    const float* __restrict__ fill_acc, const float* __restrict__ ft,
    const float* __restrict__ parts, float* __restrict__ out)
{
  __shared__ float red[16];
  const int tid = threadIdx.x;
  float s = 0.0f;
  #pragma unroll
  for (int i = 0; i < 8; ++i) s += parts[tid + i * 1024];
  if (tid < K_CL) {
    float v = fill_acc[tid] * (1.0f / (float)N_PTS) - ft[tid];
    s += v * v * (1.0f / (float)K_CL);
  }
  #pragma unroll
  for (int off = 32; off > 0; off >>= 1) s += __shfl_down(s, off);
  if ((tid & 63) == 0) red[tid >> 6] = s;
  __syncthreads();
  if (tid == 0) {
    float tot = 0.0f;
    #pragma unroll
    for (int w = 0; w < 16; ++w) tot += red[w];
    out[0] = tot;
  }
}

extern "C" void kernel_launch(void* const* d_in, const int* in_sizes, int n_in,
                              void* d_out, int out_size, void* d_ws, size_t ws_size,
                              hipStream_t stream)
{
  (void)in_sizes; (void)n_in; (void)out_size; (void)ws_size;
  const float* x      = (const float*)d_in[0];
  const float* target = (const float*)d_in[1];
  const float* cc     = (const float*)d_in[2];
  const int*   pred_t = (const int*)d_in[3];
  const float* ft     = (const float*)d_in[4];
  float* out = (float*)d_out;

  char* ws = (char*)d_ws;
  float* fill_acc = (float*)(ws + 0);
  int*   pred_x   = (int*)(ws + 1024);
  int*   idx_x    = (int*)(ws + 263168);
  int*   idx_t    = (int*)(ws + 263168 + 4194304);
  int*   count_x  = (int*)(ws + 263168 + 8388608);
  int*   count_t  = (int*)(ws + 263168 + 8388608 + 512);
  float* parts    = (float*)(ws + 263168 + 8388608 + 1024);

  k_zero<<<1, 256, 0, stream>>>((float*)ws);
  k_pred_fill<<<N_PTS / 128, 512, 0, stream>>>(x, cc, fill_acc, pred_x);
  k_scatter<<<K_CL * 2, 1024, 0, stream>>>(pred_x, pred_t, idx_x, idx_t,
                                           count_x, count_t);
  k_w1_all<<<8192 + 1024, 512, 0, stream>>>(x, target, idx_x, idx_t,
                                            count_x, count_t, parts);
  k_final<<<1, 1024, 0, stream>>>(fill_acc, ft, parts, out);
}

// Round 10
// 381.073 us; speedup vs baseline: 1.4483x; 1.4483x over previous
//
#include <hip/hip_runtime.h>
#include <math.h>

#define N_PTS 65536
#define DIM   64
#define K_CL  128
#define EPSV  1e-8f
#define CAP   8192

// ---------------- ws layout (bytes) ----------------
// 0        : fill_acc[128] float
// 1024     : pred_x[N] int
// 263168   : idx_x[128*CAP] int
// +4194304 : idx_t[128*CAP] int
// 8651776  : count_x[128], +512: count_t[128]
// 8652800  : parts[8192] float
// 8685568  : sumw[N] float
// 8947712  : inv_sumw[N] float
// 9209856  : pred_enc[N] u64

__global__ __launch_bounds__(256) void k_init(
    float* __restrict__ fill_acc, float* __restrict__ sumw,
    unsigned long long* __restrict__ pred_enc) {
  const int i = blockIdx.x * 256 + threadIdx.x;
  if (i < K_CL) fill_acc[i] = 0.0f;
  sumw[i] = 0.0f;
  pred_enc[i] = 0xFFFFFFFFFFFFFFFFull;
}

// Block-level K-split: block (pb, kb) handles 256 points x 32 clusters.
// jbase = kb*32 is blockIdx-derived -> SGPR-uniform -> centers scalarized.
// 256-thr blocks, NO min-wave floor (R9 lesson: forcing occupancy spills
// xr[64] to scratch). Partial argmin via encoded atomicMin (exact
// first-index tie-break), partial sumw via atomicAdd.
__global__ __launch_bounds__(256) void k_dist1(
    const float* __restrict__ x, const float* __restrict__ centers,
    float* __restrict__ sumw, unsigned long long* __restrict__ pred_enc)
{
  __shared__ float csq[32];
  const int kb    = blockIdx.x & 3;
  const int pb    = blockIdx.x >> 2;
  const int jbase = kb << 5;             // block-uniform!
  const int tid   = threadIdx.x;
  const int p     = pb * 256 + tid;

  if (tid < 32) {
    const float* cp = centers + (jbase + tid) * DIM;
    float s = 0.0f;
    #pragma unroll 8
    for (int d = 0; d < DIM; ++d) { float v = cp[d]; s += v * v; }
    csq[tid] = s;
  }

  float xr[DIM];
  const float4* xp = reinterpret_cast<const float4*>(x + (size_t)p * DIM);
  #pragma unroll
  for (int q = 0; q < DIM / 4; ++q) {
    float4 v = xp[q];
    xr[4 * q + 0] = v.x; xr[4 * q + 1] = v.y;
    xr[4 * q + 2] = v.z; xr[4 * q + 3] = v.w;
  }
  float xsq = 0.0f;
  #pragma unroll
  for (int d = 0; d < DIM; ++d) xsq += xr[d] * xr[d];
  __syncthreads();

  float sw = 0.0f, best = INFINITY;
  int   bj = jbase;
  #pragma unroll 2
  for (int jj = 0; jj < 32; ++jj) {
    const int j = jbase + jj;
    const float* cp = centers + j * DIM;   // uniform -> s_load
    float d0 = 0.f, d1 = 0.f, d2a = 0.f, d3 = 0.f;
    #pragma unroll
    for (int d = 0; d < DIM; d += 4) {
      d0  += xr[d + 0] * cp[d + 0];
      d1  += xr[d + 1] * cp[d + 1];
      d2a += xr[d + 2] * cp[d + 2];
      d3  += xr[d + 3] * cp[d + 3];
    }
    float dot  = (d0 + d1) + (d2a + d3);
    float dsq  = xsq + csq[jj] - 2.0f * dot;
    float dist = sqrtf(fmaxf(dsq, 0.0f));
    sw += 1.0f / (dist + EPSV);
    if (dist < best) { best = dist; bj = j; }
  }
  atomicAdd(&sumw[p], sw);
  const unsigned long long enc =
      ((unsigned long long)__float_as_uint(best) << 32) | (unsigned int)bj;
  atomicMin(&pred_enc[p], enc);
}

__global__ __launch_bounds__(256) void k_pred(
    const unsigned long long* __restrict__ pred_enc,
    const float* __restrict__ sumw,
    int* __restrict__ pred_x, float* __restrict__ inv_sumw) {
  const int p = blockIdx.x * 256 + threadIdx.x;
  pred_x[p]   = (int)(pred_enc[p] & 0xFFFFFFFFull);
  inv_sumw[p] = 1.0f / sumw[p];
}

// Pass 2 with the same block-level split: recompute w (cheaper than
// storing 32 MB), normalize by inv_sumw, reduce per cluster.
__global__ __launch_bounds__(256) void k_dist2(
    const float* __restrict__ x, const float* __restrict__ centers,
    const float* __restrict__ inv_sumw, float* __restrict__ fill_acc)
{
  __shared__ float csq[32];
  __shared__ float fl[32];
  const int kb    = blockIdx.x & 3;
  const int pb    = blockIdx.x >> 2;
  const int jbase = kb << 5;
  const int tid   = threadIdx.x;
  const int p     = pb * 256 + tid;

  if (tid < 32) {
    const float* cp = centers + (jbase + tid) * DIM;
    float s = 0.0f;
    #pragma unroll 8
    for (int d = 0; d < DIM; ++d) { float v = cp[d]; s += v * v; }
    csq[tid] = s;
    fl[tid] = 0.0f;
  }

  float xr[DIM];
  const float4* xp = reinterpret_cast<const float4*>(x + (size_t)p * DIM);
  #pragma unroll
  for (int q = 0; q < DIM / 4; ++q) {
    float4 v = xp[q];
    xr[4 * q + 0] = v.x; xr[4 * q + 1] = v.y;
    xr[4 * q + 2] = v.z; xr[4 * q + 3] = v.w;
  }
  float xsq = 0.0f;
  #pragma unroll
  for (int d = 0; d < DIM; ++d) xsq += xr[d] * xr[d];
  const float invv = inv_sumw[p];
  __syncthreads();

  #pragma unroll 2
  for (int jj = 0; jj < 32; ++jj) {
    const float* cp = centers + (jbase + jj) * DIM;
    float d0 = 0.f, d1 = 0.f, d2a = 0.f, d3 = 0.f;
    #pragma unroll
    for (int d = 0; d < DIM; d += 4) {
      d0  += xr[d + 0] * cp[d + 0];
      d1  += xr[d + 1] * cp[d + 1];
      d2a += xr[d + 2] * cp[d + 2];
      d3  += xr[d + 3] * cp[d + 3];
    }
    float dot  = (d0 + d1) + (d2a + d3);
    float dsq  = xsq + csq[jj] - 2.0f * dot;
    float dist = sqrtf(fmaxf(dsq, 0.0f));
    float wn   = (1.0f / (dist + EPSV)) * invv;
    wn += __shfl_down(wn, 32);
    wn += __shfl_down(wn, 16);
    wn += __shfl_down(wn, 8);
    wn += __shfl_down(wn, 4);
    wn += __shfl_down(wn, 2);
    wn += __shfl_down(wn, 1);
    if ((tid & 63) == 0) atomicAdd(&fl[jj], wn);
  }
  __syncthreads();
  if (tid < 32) atomicAdd(&fill_acc[jbase + tid], fl[tid]);
}

// stable member-list build, two-phase (1 barrier):
__global__ __launch_bounds__(1024) void k_scatter(
    const int* __restrict__ pred_x, const int* __restrict__ pred_t,
    int* __restrict__ idx_x, int* __restrict__ idx_t,
    int* __restrict__ count_x, int* __restrict__ count_t)
{
  const int c    = blockIdx.x >> 1;
  const int side = blockIdx.x & 1;
  const int* __restrict__ pred = side ? pred_t : pred_x;
  int* __restrict__ out = side ? idx_t : idx_x;
  int* __restrict__ cnt = side ? count_t : count_x;

  __shared__ int wsum[16];
  const int tid = threadIdx.x, lane = tid & 63, w = tid >> 6;
  const int beg = w * 4096;

  int cw = 0;
  for (int s = 0; s < 4096; s += 64) {
    const bool m = (pred[beg + s + lane] == c);
    cw += __popcll(__ballot(m));
  }
  if (lane == 0) wsum[w] = cw;
  __syncthreads();
  int base = 0, tot = 0;
  #pragma unroll
  for (int k = 0; k < 16; ++k) { int v = wsum[k]; tot += v; if (k < w) base += v; }

  int run = base;
  for (int s = 0; s < 4096; s += 64) {
    const int i = beg + s + lane;
    const bool m = (pred[i] == c);
    unsigned long long bal = __ballot(m);
    int lp = __popcll(bal & ((1ull << lane) - 1ull));
    if (m) { int pos = run + lp; if (pos < CAP) out[c * CAP + pos] = i; }
    run += __popcll(bal);
  }
  if (tid == 0) cnt[c] = tot;
}

// ---- in-register bitonic helpers ----
__device__ __forceinline__ void ce(float& a, float& b, bool up) {
  float lo = fminf(a, b), hi = fmaxf(a, b);
  a = up ? lo : hi;
  b = up ? hi : lo;
}

__device__ __forceinline__ void merge8(float* v, bool up) {
  ce(v[0],v[4],up); ce(v[1],v[5],up); ce(v[2],v[6],up); ce(v[3],v[7],up);
  ce(v[0],v[2],up); ce(v[1],v[3],up); ce(v[4],v[6],up); ce(v[5],v[7],up);
  ce(v[0],v[1],up); ce(v[2],v[3],up); ce(v[4],v[5],up); ce(v[6],v[7],up);
}

__device__ __forceinline__ void sort8(float* v, bool up8) {
  ce(v[0],v[1],true );  ce(v[2],v[3],false); ce(v[4],v[5],true );  ce(v[6],v[7],false);
  ce(v[0],v[2],true );  ce(v[1],v[3],true );  ce(v[4],v[6],false); ce(v[5],v[7],false);
  ce(v[0],v[1],true );  ce(v[2],v[3],true );  ce(v[4],v[5],false); ce(v[6],v[7],false);
  merge8(v, up8);
}

__device__ __forceinline__ void merge16(float* v, bool up) {
  #pragma unroll
  for (int e = 0; e < 8; ++e) ce(v[e], v[e + 8], up);
  merge8(v, up);
  merge8(v + 8, up);
}

__device__ __forceinline__ void sort16(float* v, bool up16) {
  sort8(v, true);
  sort8(v + 8, false);
  merge16(v, up16);
}

__device__ __forceinline__ void stage_tail(float va[8], float vb[8],
                                           int ib, int k, bool up) {
  for (int j = (k >> 1) > 256 ? 256 : (k >> 1); j >= 8; j >>= 1) {
    const int  jl = j >> 3;
    const bool low = ((ib & j) == 0);
    const bool tm  = (up == low);
    #pragma unroll
    for (int e = 0; e < 8; ++e) {
      float p = __shfl_xor(va[e], jl, 64);
      va[e] = tm ? fminf(va[e], p) : fmaxf(va[e], p);
      float q = __shfl_xor(vb[e], jl, 64);
      vb[e] = tm ? fminf(vb[e], q) : fmaxf(vb[e], q);
    }
  }
  merge8(va, up);
  merge8(vb, up);
}

__device__ __forceinline__ void stage_tail16(float va[16], float vb[16],
                                             int ib, int k, bool up) {
  for (int j = (k >> 1) > 512 ? 512 : (k >> 1); j >= 16; j >>= 1) {
    const int  jl = j >> 4;
    const bool low = ((ib & j) == 0);
    const bool tm  = (up == low);
    #pragma unroll
    for (int e = 0; e < 16; ++e) {
      float p = __shfl_xor(va[e], jl, 64);
      va[e] = tm ? fminf(va[e], p) : fmaxf(va[e], p);
      float q = __shfl_xor(vb[e], jl, 64);
      vb[e] = tm ? fminf(vb[e], q) : fmaxf(vb[e], q);
    }
  }
  merge16(va, up);
  merge16(vb, up);
}

// Unified W1 dispatch. Blocks [0,8192): per-task role for m>1024 (adaptive
// P; LDS only for j>=1024). Blocks [8192,9216): 8 wave-tasks each (m<=1024).
__global__ __launch_bounds__(512, 4) void k_w1_all(
    const float* __restrict__ x, const float* __restrict__ t,
    const int* __restrict__ idx_x, const int* __restrict__ idx_t,
    const int* __restrict__ count_x, const int* __restrict__ count_t,
    float* __restrict__ parts)
{
  __shared__ float sa[8192];   // 32 KB
  __shared__ float sb[8192];   // 32 KB
  __shared__ float red[8];
  const int tid = threadIdx.x;

  if (blockIdx.x < 8192) {
    const int task = blockIdx.x;
    const int c = task >> 6, d = task & 63;
    const int m = min(min(count_x[c], CAP), min(count_t[c], CAP));
    if (m <= 1024) return;
    int P = 2048;
    while (P < m) P <<= 1;

    const int ib  = tid << 4;
    const bool active = (ib < P);
    const int gb  = c * CAP + ib;
    float va[16], vb[16];
    if (active) {
      #pragma unroll
      for (int e = 0; e < 16; ++e) {
        if (ib + e < m) {
          va[e] = x[(size_t)idx_x[gb + e] * DIM + d];
          vb[e] = t[(size_t)idx_t[gb + e] * DIM + d];
        } else { va[e] = INFINITY; vb[e] = INFINITY; }
      }
      const bool u16 = ((ib & 16) == 0);
      sort16(va, u16);
      sort16(vb, u16);
    }

    for (int k = 32; k <= P; k <<= 1) {
      const bool up = ((ib & k) == 0);
      for (int j = k >> 1; j >= 1024; j >>= 1) {
        __syncthreads();
        if (active) {
          #pragma unroll
          for (int q = 0; q < 4; ++q) {
            *(float4*)&sa[ib + 4*q] = make_float4(va[4*q],va[4*q+1],va[4*q+2],va[4*q+3]);
            *(float4*)&sb[ib + 4*q] = make_float4(vb[4*q],vb[4*q+1],vb[4*q+2],vb[4*q+3]);
          }
        }
        __syncthreads();
        if (active) {
          const int pi = ib ^ j;
          const bool tm = (up == ((ib & j) == 0));
          #pragma unroll
          for (int q = 0; q < 4; ++q) {
            float4 A = *(const float4*)&sa[pi + 4*q];
            float4 B = *(const float4*)&sb[pi + 4*q];
            va[4*q+0] = tm ? fminf(va[4*q+0],A.x) : fmaxf(va[4*q+0],A.x);
            va[4*q+1] = tm ? fminf(va[4*q+1],A.y) : fmaxf(va[4*q+1],A.y);
            va[4*q+2] = tm ? fminf(va[4*q+2],A.z) : fmaxf(va[4*q+2],A.z);
            va[4*q+3] = tm ? fminf(va[4*q+3],A.w) : fmaxf(va[4*q+3],A.w);
            vb[4*q+0] = tm ? fminf(vb[4*q+0],B.x) : fmaxf(vb[4*q+0],B.x);
            vb[4*q+1] = tm ? fminf(vb[4*q+1],B.y) : fmaxf(vb[4*q+1],B.y);
            vb[4*q+2] = tm ? fminf(vb[4*q+2],B.z) : fmaxf(vb[4*q+2],B.z);
            vb[4*q+3] = tm ? fminf(vb[4*q+3],B.w) : fmaxf(vb[4*q+3],B.w);
          }
        }
      }
      if (active) stage_tail16(va, vb, ib, k, up);
    }

    float s = 0.0f;
    if (active) {
      #pragma unroll
      for (int e = 0; e < 16; ++e)
        if (ib + e < m) s += fabsf(va[e] - vb[e]);
    }
    #pragma unroll
    for (int off = 32; off > 0; off >>= 1) s += __shfl_down(s, off);
    __syncthreads();
    if ((tid & 63) == 0) red[tid >> 6] = s;
    __syncthreads();
    if (tid == 0) {
      float tot = 0.0f;
      #pragma unroll
      for (int w = 0; w < 8; ++w) tot += red[w];
      parts[task] = tot / (float)(m * DIM);
    }
  } else {
    const int task = (blockIdx.x - 8192) * 8 + (tid >> 6);
    const int lane = tid & 63;
    const int c = task >> 6, d = task & 63;
    const int m = min(min(count_x[c], CAP), min(count_t[c], CAP));
    if (m > 1024) return;
    if (m == 0) { if (lane == 0) parts[task] = 0.0f; return; }

    float s = 0.0f;
    if (m <= 512) {
      int P = 8;
      while (P < m) P <<= 1;
      const int ib = lane << 3;
      const int gb = c * CAP + ib;
      float va[8], vb[8];
      #pragma unroll
      for (int e = 0; e < 8; ++e) {
        if (ib + e < m) {
          va[e] = x[(size_t)idx_x[gb + e] * DIM + d];
          vb[e] = t[(size_t)idx_t[gb + e] * DIM + d];
        } else { va[e] = INFINITY; vb[e] = INFINITY; }
      }
      const bool u8 = ((ib & 8) == 0);
      sort8(va, u8);
      sort8(vb, u8);
      for (int k = 16; k <= P; k <<= 1)
        stage_tail(va, vb, ib, k, ((ib & k) == 0));
      #pragma unroll
      for (int e = 0; e < 8; ++e)
        if (ib + e < m) s += fabsf(va[e] - vb[e]);
    } else {
      const int ib = lane << 4;
      const int gb = c * CAP + ib;
      float va[16], vb[16];
      #pragma unroll
      for (int e = 0; e < 16; ++e) {
        if (ib + e < m) {
          va[e] = x[(size_t)idx_x[gb + e] * DIM + d];
          vb[e] = t[(size_t)idx_t[gb + e] * DIM + d];
        } else { va[e] = INFINITY; vb[e] = INFINITY; }
      }
      const bool u16 = ((ib & 16) == 0);
      sort16(va, u16);
      sort16(vb, u16);
      for (int k = 32; k <= 1024; k <<= 1)
        stage_tail16(va, vb, ib, k, ((ib & k) == 0));
      #pragma unroll
      for (int e = 0; e < 16; ++e)
        if (ib + e < m) s += fabsf(va[e] - vb[e]);
    }
    #pragma unroll
    for (int off = 32; off > 0; off >>= 1) s += __shfl_down(s, off);
    if (lane == 0) parts[task] = s / (float)(m * DIM);
  }
}

__global__ __launch_bounds__(1024) void k_final(
    const float* __restrict__ fill_acc, const float* __restrict__ ft,
    const float* __restrict__ parts, float* __restrict__ out)
{
  __shared__ float red[16];
  const int tid = threadIdx.x;
  float s = 0.0f;
  #pragma unroll
  for (int i = 0; i < 8; ++i) s += parts[tid + i * 1024];
  if (tid < K_CL) {
    float v = fill_acc[tid] * (1.0f / (float)N_PTS) - ft[tid];
    s += v * v * (1.0f / (float)K_CL);
  }
  #pragma unroll
  for (int off = 32; off > 0; off >>= 1) s += __shfl_down(s, off);
  if ((tid & 63) == 0) red[tid >> 6] = s;
  __syncthreads();
  if (tid == 0) {
    float tot = 0.0f;
    #pragma unroll
    for (int w = 0; w < 16; ++w) tot += red[w];
    out[0] = tot;
  }
}

extern "C" void kernel_launch(void* const* d_in, const int* in_sizes, int n_in,
                              void* d_out, int out_size, void* d_ws, size_t ws_size,
                              hipStream_t stream)
{
  (void)in_sizes; (void)n_in; (void)out_size; (void)ws_size;
  const float* x      = (const float*)d_in[0];
  const float* target = (const float*)d_in[1];
  const float* cc     = (const float*)d_in[2];
  const int*   pred_t = (const int*)d_in[3];
  const float* ft     = (const float*)d_in[4];
  float* out = (float*)d_out;

  char* ws = (char*)d_ws;
  float* fill_acc = (float*)(ws + 0);
  int*   pred_x   = (int*)(ws + 1024);
  int*   idx_x    = (int*)(ws + 263168);
  int*   idx_t    = (int*)(ws + 263168 + 4194304);
  int*   count_x  = (int*)(ws + 8651776);
  int*   count_t  = (int*)(ws + 8651776 + 512);
  float* parts    = (float*)(ws + 8652800);
  float* sumw     = (float*)(ws + 8685568);
  float* inv_sumw = (float*)(ws + 8947712);
  unsigned long long* pred_enc = (unsigned long long*)(ws + 9209856);

  k_init<<<N_PTS / 256, 256, 0, stream>>>(fill_acc, sumw, pred_enc);
  k_dist1<<<N_PTS / 256 * 4, 256, 0, stream>>>(x, cc, sumw, pred_enc);
  k_pred<<<N_PTS / 256, 256, 0, stream>>>(pred_enc, sumw, pred_x, inv_sumw);
  k_dist2<<<N_PTS / 256 * 4, 256, 0, stream>>>(x, cc, inv_sumw, fill_acc);
  k_scatter<<<K_CL * 2, 1024, 0, stream>>>(pred_x, pred_t, idx_x, idx_t,
                                           count_x, count_t);
  k_w1_all<<<8192 + 1024, 512, 0, stream>>>(x, target, idx_x, idx_t,
                                            count_x, count_t, parts);
  k_final<<<1, 1024, 0, stream>>>(fill_acc, ft, parts, out);
}